// Round 9
// baseline (187.091 us; speedup 1.0000x reference)
//
#include <hip/hip_runtime.h>
#include <hip/hip_bf16.h>

typedef __attribute__((ext_vector_type(8))) short bf16x8;
typedef __attribute__((ext_vector_type(4))) float f32x4;
typedef __attribute__((ext_vector_type(16))) float f32x16;

#define B_DIM  2
#define S_DIM  2048
#define D_DIM  1024
#define H_DIM  16
#define HD_DIM 64

__device__ __forceinline__ float bf2f(ushort u) {
    union { unsigned int ui; float f; } c; c.ui = ((unsigned int)u) << 16; return c.f;
}
__device__ __forceinline__ ushort f2bf(float f) {
    __hip_bfloat16 h = __float2bfloat16(f);
    return *reinterpret_cast<ushort*>(&h);
}

// Async global->LDS DMA, 16 B per lane. LDS dest = wave-uniform base + lane*16.
__device__ __forceinline__ void async_cp16(const ushort* g, ushort* l) {
    __builtin_amdgcn_global_load_lds(
        (const __attribute__((address_space(1))) void*)g,
        (__attribute__((address_space(3))) void*)l, 16, 0, 0);
}

// pack two f32 -> one u32 of 2 bf16 (lo = first arg), RNE
__device__ __forceinline__ unsigned int cvt_pk_bf16(float lo, float hi) {
    unsigned int d;
    asm volatile("v_cvt_pk_bf16_f32 %0, %1, %2" : "=v"(d) : "v"(lo), "v"(hi));
    return d;
}
// after: a' = [a.lo32 | b.lo32], b' = [a.hi32 | b.hi32]
__device__ __forceinline__ void pl32swap(unsigned int& a, unsigned int& b) {
    asm volatile("v_permlane32_swap_b32 %0, %1" : "+v"(a), "+v"(b));
}

// device-side bias fetch: raw pointer, dtype branch (wave-uniform)
__device__ __forceinline__ float bias_at(const void* p, int j, int isf32) {
    return isf32 ? ((const float*)p)[j] : bf2f(((const ushort*)p)[j]);
}

// ---------------------------------------------------------------------------
// Merged prep: grid (16,16,5). Detection is INLINE (R8 lesson: in_sizes are
// element counts -- dtype is NOT host-decidable). Every block samples the
// same first 16384 ushorts of x (32KB, L2-broadcast; 8192 fp32 low-halves ->
// miss prob ~e^-32; deterministic across blocks). Block (0,0,0) publishes
// the flag for the downstream GEMMs.
//   z in 0..3 : convert + transpose weight z (Q/K/V -> Wqkvt slices, O -> Wot)
//   z == 4   : canonicalize x -> bf16 (early-out when input already bf16)
// ---------------------------------------------------------------------------
__global__ __launch_bounds__(256) void prep_kernel(const void* __restrict__ x,
                                                   const void* __restrict__ Wq,
                                                   const void* __restrict__ Wk,
                                                   const void* __restrict__ Wv,
                                                   const void* __restrict__ Wo,
                                                   ushort* __restrict__ xc,
                                                   ushort* __restrict__ Wqkvt,
                                                   ushort* __restrict__ Wot,
                                                   int* __restrict__ flag) {
    __shared__ int s_any;
    int tid = threadIdx.x;
    int z = blockIdx.z;

    // ---- inline dtype detection (all blocks, fixed sample region) ----
    if (tid == 0) s_any = 0;
    __syncthreads();
    {
        int cnt = 0;
#pragma unroll
        for (int c = 0; c < 8; ++c) {
            bf16x8 v = *(const bf16x8*)&((const ushort*)x)[tid * 64 + c * 8];
#pragma unroll
            for (int e = 0; e < 8; ++e) {
                ushort u = (ushort)v[e];
                cnt += (((u >> 7) & 0xFF) == 0xFF) ? 1 : 0;
            }
        }
        if (cnt) atomicOr(&s_any, 1);
    }
    __syncthreads();
    bool isf32 = (s_any != 0);
    if (tid == 0 && blockIdx.x == 0 && blockIdx.y == 0 && z == 0)
        *flag = isf32 ? 1 : 0;

    if (z == 4) {
        if (!isf32) return;                               // raw bf16 x used directly
        int t = (blockIdx.y * 16 + blockIdx.x) * 256 + tid;   // 0..65535
#pragma unroll
        for (int c = 0; c < 8; ++c) {
            int i = t + c * 65536;                            // elem8 index
            const float* s = (const float*)x;
            f32x4 a = *(const f32x4*)&s[(size_t)i * 8];
            f32x4 b = *(const f32x4*)&s[(size_t)i * 8 + 4];
            bf16x8 o;
            o[0] = f2bf(a.x); o[1] = f2bf(a.y); o[2] = f2bf(a.z); o[3] = f2bf(a.w);
            o[4] = f2bf(b.x); o[5] = f2bf(b.y); o[6] = f2bf(b.z); o[7] = f2bf(b.w);
            *(bf16x8*)&xc[(size_t)i * 8] = o;
        }
        return;
    }

    // weight transpose
    __shared__ ushort tile[64][72];
    const void* src = (z == 0) ? Wq : (z == 1) ? Wk : (z == 2) ? Wv : Wo;
    ushort* dst = (z < 3) ? (Wqkvt + (size_t)z * D_DIM * D_DIM) : Wot;
    int r0 = blockIdx.y * 64, c0 = blockIdx.x * 64;
#pragma unroll
    for (int p = 0; p < 2; ++p) {
        int r = p * 32 + (tid >> 3);
        int c = (tid & 7) * 8;
        if (isf32) {
            const float* s = (const float*)src;
            f32x4 a = *(const f32x4*)&s[(size_t)(r0 + r) * D_DIM + c0 + c];
            f32x4 b = *(const f32x4*)&s[(size_t)(r0 + r) * D_DIM + c0 + c + 4];
            tile[r][c + 0] = f2bf(a.x); tile[r][c + 1] = f2bf(a.y);
            tile[r][c + 2] = f2bf(a.z); tile[r][c + 3] = f2bf(a.w);
            tile[r][c + 4] = f2bf(b.x); tile[r][c + 5] = f2bf(b.y);
            tile[r][c + 6] = f2bf(b.z); tile[r][c + 7] = f2bf(b.w);
        } else {
            *(bf16x8*)&tile[r][c] =
                *(const bf16x8*)&((const ushort*)src)[(size_t)(r0 + r) * D_DIM + c0 + c];
        }
    }
    __syncthreads();
#pragma unroll
    for (int p = 0; p < 2; ++p) {
        int n  = p * 32 + (tid >> 3);
        int cc = (tid & 7) * 8;
        bf16x8 v;
#pragma unroll
        for (int e = 0; e < 8; ++e) v[e] = (short)tile[cc + e][n];
        *(bf16x8*)&dst[(size_t)(c0 + n) * D_DIM + r0 + cc] = v;
    }
}

// ---------------------------------------------------------------------------
// Fused QKV GEMM: 128x128 tile, BK=64, global_load_lds(16B), XOR swizzle.
// A selected device-side from *flag (raw x when bf16, converted xc when f32).
// Q -> (BH,S,64) bf16 (pre-scaled 0.125*log2e).
// K -> FRAGMENT-PACKED Kp[bh][t][mb][jm][hi][l31][e]; V fragment-packed too.
// Biases read raw (dtype branch) in the epilogue.
// ---------------------------------------------------------------------------
__global__ __launch_bounds__(256) void gemm128_kernel(const void* __restrict__ xraw,
                                                      const ushort* __restrict__ xc,
                                                      const ushort* __restrict__ Bt,
                                                      const void* __restrict__ bq,
                                                      const void* __restrict__ bk,
                                                      const void* __restrict__ bv,
                                                      ushort* __restrict__ qout,
                                                      ushort* __restrict__ kpout,
                                                      ushort* __restrict__ vpout,
                                                      const int* __restrict__ flag) {
    __shared__ ushort As[128 * 64];   // 16 KiB, unpadded
    __shared__ ushort Bs[128 * 64];
    int isf32 = *flag;
    const ushort* A = isf32 ? xc : (const ushort*)xraw;
    int tid  = threadIdx.x;
    int wave = tid >> 6;
    int lane = tid & 63;
    int l16  = lane & 15;
    int quad = lane >> 4;
    int m0   = blockIdx.y * 128;
    int n0   = blockIdx.x * 128;
    int wm   = wave >> 1;
    int wn   = wave & 1;
    const int K = 1024;

    f32x4 acc[4][4];
#pragma unroll
    for (int i = 0; i < 4; ++i)
#pragma unroll
        for (int j = 0; j < 4; ++j) acc[i][j] = (f32x4){0.f, 0.f, 0.f, 0.f};

    int lrow = lane >> 3;                         // 0..7 row within chunk
    int gcol = ((lane & 7) ^ lrow) * 8;           // swizzled column (elems)
    int sw   = l16 & 7;                           // fragment-read swizzle

    for (int kt = 0; kt < 16; ++kt) {
        int k0 = kt * 64;
#pragma unroll
        for (int j = 0; j < 4; ++j) {
            int chunk = wave * 4 + j;             // 0..15; 8 rows each
            int grow  = chunk * 8 + lrow;
            async_cp16(&A[(size_t)(m0 + grow) * K + k0 + gcol], &As[chunk * 512]);
            async_cp16(&Bt[(size_t)(n0 + grow) * K + k0 + gcol], &Bs[chunk * 512]);
        }
        __syncthreads();

#pragma unroll
        for (int kb = 0; kb < 2; ++kb) {
            bf16x8 af[4], bf[4];
#pragma unroll
            for (int i = 0; i < 4; ++i)
                af[i] = *(const bf16x8*)&As[(wm * 64 + i * 16 + l16) * 64 +
                                            (((kb * 4 + quad) ^ sw) << 3)];
#pragma unroll
            for (int j = 0; j < 4; ++j)
                bf[j] = *(const bf16x8*)&Bs[(wn * 64 + j * 16 + l16) * 64 +
                                            (((kb * 4 + quad) ^ sw) << 3)];
#pragma unroll
            for (int i = 0; i < 4; ++i)
#pragma unroll
                for (int j = 0; j < 4; ++j)
                    acc[i][j] = __builtin_amdgcn_mfma_f32_16x16x32_bf16(af[i], bf[j],
                                                                        acc[i][j], 0, 0, 0);
        }
        __syncthreads();
    }

#pragma unroll
    for (int j = 0; j < 4; ++j) {
        int n = n0 + wn * 64 + j * 16 + l16;        // C/D col = lane&15
        int which = n >> 10;                        // 0=Q 1=K 2=V
        int n1 = n & 1023;
        const void* bp = (which == 0) ? bq : (which == 1) ? bk : bv;
        float bvv = bias_at(bp, n1, isf32);
        int h = n1 >> 6, hd = n1 & 63;
#pragma unroll
        for (int i = 0; i < 4; ++i) {
            int mb = m0 + wm * 64 + i * 16 + quad * 4;     // row base (quad*4)
            int b = mb >> 11, s = mb & (S_DIM - 1);
            int bh = b * H_DIM + h;
            float v4[4];
#pragma unroll
            for (int r = 0; r < 4; ++r) v4[r] = acc[i][j][r] + bvv;
            if (which == 2) {
                // V fragment-packed; s..s+3 contiguous e -> uint2 store
                ushort pk[4];
#pragma unroll
                for (int r = 0; r < 4; ++r) pk[r] = f2bf(v4[r]);
                size_t vidx = (size_t)bh * 131072 + (size_t)(s >> 6) * 4096 +
                              (size_t)((s >> 4) & 3) * 1024 + (size_t)(hd >> 5) * 512 +
                              (size_t)((s >> 3) & 1) * 256 + (size_t)(hd & 31) * 8 +
                              (s & 7);
                *(uint2*)&vpout[vidx] = *(uint2*)pk;
            } else if (which == 1) {
                // K fragment-packed; 4 scalar stores (stride 8 elems)
#pragma unroll
                for (int r = 0; r < 4; ++r) {
                    int key = s + r;
                    size_t kidx = (size_t)bh * 131072 + (size_t)(key >> 6) * 4096 +
                                  (size_t)((key >> 5) & 1) * 2048 +
                                  (size_t)(hd >> 4) * 512 +
                                  (size_t)((hd >> 3) & 1) * 256 +
                                  (size_t)(key & 31) * 8 + (hd & 7);
                    kpout[kidx] = f2bf(v4[r]);
                }
            } else {
#pragma unroll
                for (int r = 0; r < 4; ++r) {
                    // fold softmax scale AND log2(e) into Q (attn uses exp2)
                    float v = v4[r] * 0.18033688011f;      // 0.125 * log2(e)
                    qout[((((size_t)bh) * S_DIM + s + r) << 6) + hd] = f2bf(v);
                }
            }
        }
    }
}

// ---------------------------------------------------------------------------
// O-projection GEMM: 64x128 tile (M x N), BK=64, same staging/swizzle.
// ---------------------------------------------------------------------------
__global__ __launch_bounds__(256) void gemm64_kernel(const ushort* __restrict__ A,
                                                     const ushort* __restrict__ Bt,
                                                     const void* __restrict__ bo,
                                                     void* __restrict__ out,
                                                     const int* __restrict__ flag) {
    __shared__ ushort As[64 * 64];    // 8 KiB
    __shared__ ushort Bs[128 * 64];   // 16 KiB
    int isf32 = *flag;
    int tid  = threadIdx.x;
    int wave = tid >> 6;
    int lane = tid & 63;
    int l16  = lane & 15;
    int quad = lane >> 4;
    int m0   = blockIdx.y * 64;
    int n0   = blockIdx.x * 128;
    const int K = 1024;

    f32x4 acc[4][2];
#pragma unroll
    for (int i = 0; i < 4; ++i)
#pragma unroll
        for (int j = 0; j < 2; ++j) acc[i][j] = (f32x4){0.f, 0.f, 0.f, 0.f};

    int lrow = lane >> 3;
    int gcol = ((lane & 7) ^ lrow) * 8;
    int sw   = l16 & 7;

    for (int kt = 0; kt < 16; ++kt) {
        int k0 = kt * 64;
        // A: 8 chunks (2 per wave); B: 16 chunks (4 per wave)
#pragma unroll
        for (int j = 0; j < 2; ++j) {
            int chunk = wave * 2 + j;
            int grow  = chunk * 8 + lrow;
            async_cp16(&A[(size_t)(m0 + grow) * K + k0 + gcol], &As[chunk * 512]);
        }
#pragma unroll
        for (int j = 0; j < 4; ++j) {
            int chunk = wave * 4 + j;
            int grow  = chunk * 8 + lrow;
            async_cp16(&Bt[(size_t)(n0 + grow) * K + k0 + gcol], &Bs[chunk * 512]);
        }
        __syncthreads();

#pragma unroll
        for (int kb = 0; kb < 2; ++kb) {
            bf16x8 af[4], bf[2];
#pragma unroll
            for (int i = 0; i < 4; ++i)
                af[i] = *(const bf16x8*)&As[(i * 16 + l16) * 64 +
                                            (((kb * 4 + quad) ^ sw) << 3)];
#pragma unroll
            for (int j = 0; j < 2; ++j)
                bf[j] = *(const bf16x8*)&Bs[(wave * 32 + j * 16 + l16) * 64 +
                                            (((kb * 4 + quad) ^ sw) << 3)];
#pragma unroll
            for (int i = 0; i < 4; ++i)
#pragma unroll
                for (int j = 0; j < 2; ++j)
                    acc[i][j] = __builtin_amdgcn_mfma_f32_16x16x32_bf16(af[i], bf[j],
                                                                        acc[i][j], 0, 0, 0);
        }
        __syncthreads();
    }

#pragma unroll
    for (int j = 0; j < 2; ++j) {
        int n = n0 + wave * 32 + j * 16 + l16;
        float bvv = bias_at(bo, n, isf32);
#pragma unroll
        for (int i = 0; i < 4; ++i)
#pragma unroll
            for (int r = 0; r < 4; ++r) {
                int m = m0 + i * 16 + quad * 4 + r;
                float v = acc[i][j][r] + bvv;
                if (isf32) ((float*)out)[(size_t)m * D_DIM + n] = v;
                else       ((ushort*)out)[(size_t)m * D_DIM + n] = f2bf(v);
            }
    }
}

// ---------------------------------------------------------------------------
// Causal attention v7: barrier-free, LDS-free per-wave streaming + XCD pin.
// (unchanged from R7 -- verified structure)
// ---------------------------------------------------------------------------
#define LOADK(DST, T) { size_t _b = Kbase + (size_t)(T) * 4096 + lane8;           \
    _Pragma("unroll") for (int _i = 0; _i < 8; ++_i)                              \
        DST[_i] = *(const bf16x8*)&Kp[_b + (size_t)((_i >> 2) * 2048 + (_i & 3) * 512)]; }

#define LOADV(DST, T) { size_t _b = Vbase + (size_t)(T) * 4096 + lane8;           \
    _Pragma("unroll") for (int _i = 0; _i < 8; ++_i)                              \
        DST[_i] = *(const bf16x8*)&Vp[_b + (size_t)((_i >> 1) * 1024 + (_i & 1) * 512)]; }

#define SOFT(SC, P0, P1) { unsigned int W[8];                                     \
    _Pragma("unroll") for (int _g = 0; _g < 4; ++_g) {                            \
        float _e0 = __builtin_amdgcn_exp2f(SC[4 * _g + 0]);                       \
        float _e1 = __builtin_amdgcn_exp2f(SC[4 * _g + 1]);                       \
        float _e2 = __builtin_amdgcn_exp2f(SC[4 * _g + 2]);                       \
        float _e3 = __builtin_amdgcn_exp2f(SC[4 * _g + 3]);                       \
        rsum += (_e0 + _e1) + (_e2 + _e3);                                        \
        W[2 * _g]     = cvt_pk_bf16(_e0, _e1);                                    \
        W[2 * _g + 1] = cvt_pk_bf16(_e2, _e3); }                                  \
    pl32swap(W[0], W[2]); pl32swap(W[1], W[3]);                                   \
    pl32swap(W[4], W[6]); pl32swap(W[5], W[7]);                                   \
    { union { unsigned int u[4]; bf16x8 v; } _c0, _c1;                            \
      _c0.u[0] = W[0]; _c0.u[1] = W[1]; _c0.u[2] = W[2]; _c0.u[3] = W[3];         \
      _c1.u[0] = W[4]; _c1.u[1] = W[5]; _c1.u[2] = W[6]; _c1.u[3] = W[7];         \
      P0 = _c0.v; P1 = _c1.v; } }

#define ROUND(KC, VC, KN, VN, T, PRE) {                                           \
    if (PRE) { LOADK(KN, (T) + 1); LOADV(VN, (T) + 1); }                          \
    int k0 = (T) * 64;                                                            \
    f32x16 sc0, sc1;                                                              \
    _Pragma("unroll") for (int _r = 0; _r < 16; ++_r) { sc0[_r] = 0.f; sc1[_r] = 0.f; } \
    __builtin_amdgcn_s_setprio(1);                                                \
    _Pragma("unroll") for (int _j = 0; _j < 4; ++_j) {                            \
        sc0 = __builtin_amdgcn_mfma_f32_32x32x16_bf16(KC[_j],     qf[_j], sc0, 0, 0, 0); \
        sc1 = __builtin_amdgcn_mfma_f32_32x32x16_bf16(KC[4 + _j], qf[_j], sc1, 0, 0, 0); } \
    __builtin_amdgcn_s_setprio(0);                                                \
    if (k0 + 63 > qmin) {                                                         \
        int qglob = qmin + l31;                                                   \
        _Pragma("unroll") for (int _r = 0; _r < 16; ++_r) {                       \
            int krow = k0 + (_r & 3) + 8 * (_r >> 2) + 4 * hi;                    \
            if (krow > qglob)      sc0[_r] = -1e30f;                              \
            if (krow + 32 > qglob) sc1[_r] = -1e30f; } }                          \
    bf16x8 pf[4];                                                                 \
    SOFT(sc0, pf[0], pf[1]);                                                      \
    SOFT(sc1, pf[2], pf[3]);                                                      \
    __builtin_amdgcn_s_setprio(1);                                                \
    _Pragma("unroll") for (int _j = 0; _j < 4; ++_j) {                            \
        oo0 = __builtin_amdgcn_mfma_f32_32x32x16_bf16(pf[_j], VC[2 * _j],     oo0, 0, 0, 0); \
        oo1 = __builtin_amdgcn_mfma_f32_32x32x16_bf16(pf[_j], VC[2 * _j + 1], oo1, 0, 0, 0); } \
    __builtin_amdgcn_s_setprio(0); }

__global__ __launch_bounds__(64, 2) void attn_kernel(const ushort* __restrict__ Qg,
                                                     const ushort* __restrict__ Kp,
                                                     const ushort* __restrict__ Vp,
                                                     ushort* __restrict__ attn_out) {
    int lane = threadIdx.x;
    int l31  = lane & 31;
    int hi   = lane >> 5;
    // XCD-locality decode: bid = xcd + 8*rank; rank = qt-desc | bh-group | w.
    int bid  = blockIdx.x;              // 0..2047
    int xcd  = bid & 7;                 // presumed XCD (round-robin bid%8)
    int rank = bid >> 3;                // 0..255 within XCD
    int qt   = 15 - (rank >> 4);        // long-first within the XCD
    int rem  = rank & 15;
    int bh   = xcd + 8 * (rem >> 2);    // bh & 7 == xcd  (4 bh per XCD)
    int w    = rem & 3;                 // 32-query sub-block within the q-tile
    int qmin = qt * 128 + w * 32;
    int thw  = ((qmin + 31) >> 6) + 1;  // tiles 0..thw-1 (rest fully masked)

    size_t lane8 = (size_t)lane * 8;
    size_t Kbase = (size_t)bh * 131072;
    size_t Vbase = (size_t)bh * 131072;
    const ushort* Qb = Qg + (size_t)bh * S_DIM * HD_DIM;

    // Q fragments (B-operand: n=query=l31, k=hd = kk*16 + hi*8 + e)
    bf16x8 qf[4];
#pragma unroll
    for (int kk = 0; kk < 4; ++kk)
        qf[kk] = *(const bf16x8*)&Qb[(size_t)(qmin + l31) * HD_DIM + kk * 16 + hi * 8];

    f32x16 oo0, oo1;
#pragma unroll
    for (int r = 0; r < 16; ++r) { oo0[r] = 0.f; oo1[r] = 0.f; }
    float rsum = 0.f;

    bf16x8 kA[8], kB[8], vA[8], vB[8];
    int t = 0;
    LOADK(kA, 0); LOADV(vA, 0);
    for (; t + 2 <= thw; t += 2) {
        ROUND(kA, vA, kB, vB, t, true);
        ROUND(kB, vB, kA, vA, t + 1, (t + 2 < thw));
    }
    if (t < thw) ROUND(kA, vA, kB, vB, t, false);

    // row sum across the two key-halves held by lanes l and l+32
    rsum += __shfl_xor(rsum, 32, 64);
    float inv = 1.f / rsum;             // lane q holds inv for query qmin+q (q<32)

    // epilogue: normalized bf16 write, C-frag row = (r&3)+8*(r>>2)+4*hi
    int b = bh >> 4, h = bh & 15;
#pragma unroll
    for (int r = 0; r < 16; ++r) {
        int qrow = (r & 3) + 8 * (r >> 2) + 4 * hi;
        float iv = __shfl(inv, qrow, 64);
        int q = qmin + qrow;
        size_t base = (size_t)(b * S_DIM + q) * D_DIM + h * HD_DIM;
        attn_out[base + l31]      = f2bf(oo0[r] * iv);
        attn_out[base + 32 + l31] = f2bf(oo1[r] * iv);
    }
}

// ---------------------------------------------------------------------------
extern "C" void kernel_launch(void* const* d_in, const int* in_sizes, int n_in,
                              void* d_out, int out_size, void* d_ws, size_t ws_size,
                              hipStream_t stream) {
    const void* x  = d_in[0];
    const void* Wq = d_in[1];
    const void* bq = d_in[2];
    const void* Wk = d_in[3];
    const void* bk = d_in[4];
    const void* Wv = d_in[5];
    const void* bv = d_in[6];
    const void* Wo = d_in[7];
    const void* bo = d_in[8];
    // d_in[9] = mask: exactly causal tril, handled analytically.

    char* ws = (char*)d_ws;
    const size_t MB = 1024 * 1024;
    const size_t base = 64 * 1024;
    int*    flag   = (int*)ws;
    ushort* xc     = (ushort*)(ws + base);                  // 8 MiB; reused as attn later
    ushort* Wqkvt  = (ushort*)(ws + base + 8  * MB);        // 6 MiB (3072x1024)
    ushort* Wot    = (ushort*)(ws + base + 14 * MB);        // 2 MiB
    ushort* Qc     = (ushort*)(ws + base + 16 * MB);        // 8 MiB Q (BH,S,64)
    ushort* Kpf    = (ushort*)(ws + base + 24 * MB);        // 8 MiB K fragment-packed
    ushort* Vpf    = (ushort*)(ws + base + 40 * MB);        // 8 MiB V fragment-packed
    ushort* attn   = xc;                                    // xc dead before attn writes

    dim3 tb(256);

    // z = 0..3 weight transpose; z == 4 x->bf16 convert (early-out for bf16).
    // Detection is inline; block (0,0,0) publishes *flag for the GEMMs.
    dim3 pg(16, 16, 5);
    prep_kernel<<<pg, tb, 0, stream>>>(x, Wq, Wk, Wv, Wo, xc, Wqkvt, Wot, flag);

    // Fused QKV projection: (4096x1024) x (3072x1024)^T
    dim3 gq(3 * D_DIM / 128, (B_DIM * S_DIM) / 128);   // (24, 32)
    gemm128_kernel<<<gq, tb, 0, stream>>>(x, xc, Wqkvt, bq, bk, bv,
                                          Qc, Kpf, Vpf, flag);

    attn_kernel<<<2048, dim3(64), 0, stream>>>(Qc, Kpf, Vpf, attn);

    dim3 go(D_DIM / 128, (B_DIM * S_DIM) / 64);        // (8, 64) = 512 blocks
    gemm64_kernel<<<go, tb, 0, stream>>>(attn, Wot, bo, d_out, flag);
}

// Round 10
// 183.989 us; speedup vs baseline: 1.0169x; 1.0169x over previous
//
#include <hip/hip_runtime.h>
#include <hip/hip_bf16.h>

typedef __attribute__((ext_vector_type(8))) short bf16x8;
typedef __attribute__((ext_vector_type(4))) float f32x4;
typedef __attribute__((ext_vector_type(16))) float f32x16;

#define B_DIM  2
#define S_DIM  2048
#define D_DIM  1024
#define H_DIM  16
#define HD_DIM 64

__device__ __forceinline__ float bf2f(ushort u) {
    union { unsigned int ui; float f; } c; c.ui = ((unsigned int)u) << 16; return c.f;
}
__device__ __forceinline__ ushort f2bf(float f) {
    __hip_bfloat16 h = __float2bfloat16(f);
    return *reinterpret_cast<ushort*>(&h);
}

// Async global->LDS DMA, 16 B per lane. LDS dest = wave-uniform base + lane*16.
__device__ __forceinline__ void async_cp16(const ushort* g, ushort* l) {
    __builtin_amdgcn_global_load_lds(
        (const __attribute__((address_space(1))) void*)g,
        (__attribute__((address_space(3))) void*)l, 16, 0, 0);
}

// pack two f32 -> one u32 of 2 bf16 (lo = first arg), RNE
__device__ __forceinline__ unsigned int cvt_pk_bf16(float lo, float hi) {
    unsigned int d;
    asm volatile("v_cvt_pk_bf16_f32 %0, %1, %2" : "=v"(d) : "v"(lo), "v"(hi));
    return d;
}
// after: a' = [a.lo32 | b.lo32], b' = [a.hi32 | b.hi32]
__device__ __forceinline__ void pl32swap(unsigned int& a, unsigned int& b) {
    asm volatile("v_permlane32_swap_b32 %0, %1" : "+v"(a), "+v"(b));
}

// ---------------------------------------------------------------------------
// Dtype detector: valid bf16 inputs never have exponent bits 0xFF; fp32 read
// as u16 halves hits 0xFF with p~1/256. flag=1 -> fp32 inputs, 0 -> bf16.
// (Separate 1-block kernel: graph-captured launches are ~free -- R9 showed
// inlining this into prep COSTS ~3 us of redundant per-block reads.)
// ---------------------------------------------------------------------------
__global__ __launch_bounds__(256) void detect_kernel(const ushort* __restrict__ x,
                                                     int* __restrict__ flag) {
    __shared__ int any;
    int tid = threadIdx.x;
    if (tid == 0) any = 0;
    __syncthreads();
    int cnt = 0;
#pragma unroll
    for (int c = 0; c < 8; ++c) {
        bf16x8 v = *(const bf16x8*)&x[tid * 64 + c * 8];
#pragma unroll
        for (int e = 0; e < 8; ++e) {
            ushort u = (ushort)v[e];
            if (((u >> 7) & 0xFF) == 0xFF) cnt++;
        }
    }
    if (cnt) atomicOr(&any, 1);
    __syncthreads();
    if (tid == 0) *flag = any ? 1 : 0;
}

// ---------------------------------------------------------------------------
// Merged prep: grid (16,16,6).
//   z in 0..3 : convert + transpose weight z (Q/K/V -> Wqkvt slices, O -> Wot)
//   z == 4   : canonicalize x -> bf16 (early-out when input already bf16)
//   z == 5   : biases -> fp32 (first 16 blocks)
// ---------------------------------------------------------------------------
__global__ __launch_bounds__(256) void prep_kernel(const void* __restrict__ x,
                                                   const void* __restrict__ Wq,
                                                   const void* __restrict__ Wk,
                                                   const void* __restrict__ Wv,
                                                   const void* __restrict__ Wo,
                                                   const void* __restrict__ bq,
                                                   const void* __restrict__ bk,
                                                   const void* __restrict__ bv,
                                                   const void* __restrict__ bo,
                                                   ushort* __restrict__ xc,
                                                   ushort* __restrict__ Wqkvt,
                                                   ushort* __restrict__ Wot,
                                                   float* __restrict__ biasf,
                                                   const int* __restrict__ flag) {
    int tid = threadIdx.x;
    int z = blockIdx.z;
    bool isf32 = (*flag != 0);

    if (z == 4) {
        if (!isf32) return;                               // raw bf16 x used directly
        int t = (blockIdx.y * 16 + blockIdx.x) * 256 + tid;   // 0..65535
#pragma unroll
        for (int c = 0; c < 8; ++c) {
            int i = t + c * 65536;                            // elem8 index
            const float* s = (const float*)x;
            f32x4 a = *(const f32x4*)&s[(size_t)i * 8];
            f32x4 b = *(const f32x4*)&s[(size_t)i * 8 + 4];
            bf16x8 o;
            o[0] = f2bf(a.x); o[1] = f2bf(a.y); o[2] = f2bf(a.z); o[3] = f2bf(a.w);
            o[4] = f2bf(b.x); o[5] = f2bf(b.y); o[6] = f2bf(b.z); o[7] = f2bf(b.w);
            *(bf16x8*)&xc[(size_t)i * 8] = o;
        }
        return;
    }
    if (z == 5) {
        int bid = blockIdx.y * 16 + blockIdx.x;
        if (bid >= 16) return;
        int i = bid * 256 + tid;                              // 0..4095
        int w = i >> 10, j = i & 1023;
        const void* s = (w == 0) ? bq : (w == 1) ? bk : (w == 2) ? bv : bo;
        biasf[i] = isf32 ? ((const float*)s)[j] : bf2f(((const ushort*)s)[j]);
        return;
    }

    // weight transpose
    __shared__ ushort tile[64][72];
    const void* src = (z == 0) ? Wq : (z == 1) ? Wk : (z == 2) ? Wv : Wo;
    ushort* dst = (z < 3) ? (Wqkvt + (size_t)z * D_DIM * D_DIM) : Wot;
    int r0 = blockIdx.y * 64, c0 = blockIdx.x * 64;
#pragma unroll
    for (int p = 0; p < 2; ++p) {
        int r = p * 32 + (tid >> 3);
        int c = (tid & 7) * 8;
        if (isf32) {
            const float* s = (const float*)src;
            f32x4 a = *(const f32x4*)&s[(size_t)(r0 + r) * D_DIM + c0 + c];
            f32x4 b = *(const f32x4*)&s[(size_t)(r0 + r) * D_DIM + c0 + c + 4];
            tile[r][c + 0] = f2bf(a.x); tile[r][c + 1] = f2bf(a.y);
            tile[r][c + 2] = f2bf(a.z); tile[r][c + 3] = f2bf(a.w);
            tile[r][c + 4] = f2bf(b.x); tile[r][c + 5] = f2bf(b.y);
            tile[r][c + 6] = f2bf(b.z); tile[r][c + 7] = f2bf(b.w);
        } else {
            *(bf16x8*)&tile[r][c] =
                *(const bf16x8*)&((const ushort*)src)[(size_t)(r0 + r) * D_DIM + c0 + c];
        }
    }
    __syncthreads();
#pragma unroll
    for (int p = 0; p < 2; ++p) {
        int n  = p * 32 + (tid >> 3);
        int cc = (tid & 7) * 8;
        bf16x8 v;
#pragma unroll
        for (int e = 0; e < 8; ++e) v[e] = (short)tile[cc + e][n];
        *(bf16x8*)&dst[(size_t)(c0 + n) * D_DIM + r0 + cc] = v;
    }
}

// ---------------------------------------------------------------------------
// Fused QKV GEMM: 128x128 tile, BK=64, global_load_lds(16B), XOR swizzle.
// A selected device-side from *flag (raw x when bf16, converted xc when f32).
// Q -> (BH,S,64) bf16 (pre-scaled 0.125*log2e).
// K -> FRAGMENT-PACKED Kp[bh][t][mb][jm][hi][l31][e]; V fragment-packed too.
// ---------------------------------------------------------------------------
__global__ __launch_bounds__(256) void gemm128_kernel(const void* __restrict__ xraw,
                                                      const ushort* __restrict__ xc,
                                                      const ushort* __restrict__ Bt,
                                                      const float* __restrict__ bias,
                                                      ushort* __restrict__ qout,
                                                      ushort* __restrict__ kpout,
                                                      ushort* __restrict__ vpout,
                                                      const int* __restrict__ flag) {
    __shared__ ushort As[128 * 64];   // 16 KiB, unpadded
    __shared__ ushort Bs[128 * 64];
    const ushort* A = (*flag != 0) ? xc : (const ushort*)xraw;
    int tid  = threadIdx.x;
    int wave = tid >> 6;
    int lane = tid & 63;
    int l16  = lane & 15;
    int quad = lane >> 4;
    int m0   = blockIdx.y * 128;
    int n0   = blockIdx.x * 128;
    int wm   = wave >> 1;
    int wn   = wave & 1;
    const int K = 1024;

    f32x4 acc[4][4];
#pragma unroll
    for (int i = 0; i < 4; ++i)
#pragma unroll
        for (int j = 0; j < 4; ++j) acc[i][j] = (f32x4){0.f, 0.f, 0.f, 0.f};

    int lrow = lane >> 3;                         // 0..7 row within chunk
    int gcol = ((lane & 7) ^ lrow) * 8;           // swizzled column (elems)
    int sw   = l16 & 7;                           // fragment-read swizzle

    for (int kt = 0; kt < 16; ++kt) {
        int k0 = kt * 64;
#pragma unroll
        for (int j = 0; j < 4; ++j) {
            int chunk = wave * 4 + j;             // 0..15; 8 rows each
            int grow  = chunk * 8 + lrow;
            async_cp16(&A[(size_t)(m0 + grow) * K + k0 + gcol], &As[chunk * 512]);
            async_cp16(&Bt[(size_t)(n0 + grow) * K + k0 + gcol], &Bs[chunk * 512]);
        }
        __syncthreads();

#pragma unroll
        for (int kb = 0; kb < 2; ++kb) {
            bf16x8 af[4], bf[4];
#pragma unroll
            for (int i = 0; i < 4; ++i)
                af[i] = *(const bf16x8*)&As[(wm * 64 + i * 16 + l16) * 64 +
                                            (((kb * 4 + quad) ^ sw) << 3)];
#pragma unroll
            for (int j = 0; j < 4; ++j)
                bf[j] = *(const bf16x8*)&Bs[(wn * 64 + j * 16 + l16) * 64 +
                                            (((kb * 4 + quad) ^ sw) << 3)];
#pragma unroll
            for (int i = 0; i < 4; ++i)
#pragma unroll
                for (int j = 0; j < 4; ++j)
                    acc[i][j] = __builtin_amdgcn_mfma_f32_16x16x32_bf16(af[i], bf[j],
                                                                        acc[i][j], 0, 0, 0);
        }
        __syncthreads();
    }

#pragma unroll
    for (int j = 0; j < 4; ++j) {
        int n = n0 + wn * 64 + j * 16 + l16;        // C/D col = lane&15
        float bv = bias[n];
        int which = n >> 10;                        // 0=Q 1=K 2=V
        int n1 = n & 1023;
        int h = n1 >> 6, hd = n1 & 63;
#pragma unroll
        for (int i = 0; i < 4; ++i) {
            int mb = m0 + wm * 64 + i * 16 + quad * 4;     // row base (quad*4)
            int b = mb >> 11, s = mb & (S_DIM - 1);
            int bh = b * H_DIM + h;
            float v4[4];
#pragma unroll
            for (int r = 0; r < 4; ++r) v4[r] = acc[i][j][r] + bv;
            if (which == 2) {
                // V fragment-packed; s..s+3 contiguous e -> uint2 store
                ushort pk[4];
#pragma unroll
                for (int r = 0; r < 4; ++r) pk[r] = f2bf(v4[r]);
                size_t vidx = (size_t)bh * 131072 + (size_t)(s >> 6) * 4096 +
                              (size_t)((s >> 4) & 3) * 1024 + (size_t)(hd >> 5) * 512 +
                              (size_t)((s >> 3) & 1) * 256 + (size_t)(hd & 31) * 8 +
                              (s & 7);
                *(uint2*)&vpout[vidx] = *(uint2*)pk;
            } else if (which == 1) {
                // K fragment-packed; 4 scalar stores (stride 8 elems)
#pragma unroll
                for (int r = 0; r < 4; ++r) {
                    int key = s + r;
                    size_t kidx = (size_t)bh * 131072 + (size_t)(key >> 6) * 4096 +
                                  (size_t)((key >> 5) & 1) * 2048 +
                                  (size_t)(hd >> 4) * 512 +
                                  (size_t)((hd >> 3) & 1) * 256 +
                                  (size_t)(key & 31) * 8 + (hd & 7);
                    kpout[kidx] = f2bf(v4[r]);
                }
            } else {
#pragma unroll
                for (int r = 0; r < 4; ++r) {
                    // fold softmax scale AND log2(e) into Q (attn uses exp2)
                    float v = v4[r] * 0.18033688011f;      // 0.125 * log2(e)
                    qout[((((size_t)bh) * S_DIM + s + r) << 6) + hd] = f2bf(v);
                }
            }
        }
    }
}

// ---------------------------------------------------------------------------
// O-projection GEMM: 64x128 tile (M x N), BK=64, same staging/swizzle.
// ---------------------------------------------------------------------------
__global__ __launch_bounds__(256) void gemm64_kernel(const ushort* __restrict__ A,
                                                     const ushort* __restrict__ Bt,
                                                     const float* __restrict__ bias,
                                                     void* __restrict__ out,
                                                     const int* __restrict__ flag) {
    __shared__ ushort As[64 * 64];    // 8 KiB
    __shared__ ushort Bs[128 * 64];   // 16 KiB
    int tid  = threadIdx.x;
    int wave = tid >> 6;
    int lane = tid & 63;
    int l16  = lane & 15;
    int quad = lane >> 4;
    int m0   = blockIdx.y * 64;
    int n0   = blockIdx.x * 128;
    const int K = 1024;

    f32x4 acc[4][2];
#pragma unroll
    for (int i = 0; i < 4; ++i)
#pragma unroll
        for (int j = 0; j < 2; ++j) acc[i][j] = (f32x4){0.f, 0.f, 0.f, 0.f};

    int lrow = lane >> 3;
    int gcol = ((lane & 7) ^ lrow) * 8;
    int sw   = l16 & 7;

    for (int kt = 0; kt < 16; ++kt) {
        int k0 = kt * 64;
        // A: 8 chunks (2 per wave); B: 16 chunks (4 per wave)
#pragma unroll
        for (int j = 0; j < 2; ++j) {
            int chunk = wave * 2 + j;
            int grow  = chunk * 8 + lrow;
            async_cp16(&A[(size_t)(m0 + grow) * K + k0 + gcol], &As[chunk * 512]);
        }
#pragma unroll
        for (int j = 0; j < 4; ++j) {
            int chunk = wave * 4 + j;
            int grow  = chunk * 8 + lrow;
            async_cp16(&Bt[(size_t)(n0 + grow) * K + k0 + gcol], &Bs[chunk * 512]);
        }
        __syncthreads();

#pragma unroll
        for (int kb = 0; kb < 2; ++kb) {
            bf16x8 af[4], bf[2];
#pragma unroll
            for (int i = 0; i < 4; ++i)
                af[i] = *(const bf16x8*)&As[(i * 16 + l16) * 64 +
                                            (((kb * 4 + quad) ^ sw) << 3)];
#pragma unroll
            for (int j = 0; j < 2; ++j)
                bf[j] = *(const bf16x8*)&Bs[(wave * 32 + j * 16 + l16) * 64 +
                                            (((kb * 4 + quad) ^ sw) << 3)];
#pragma unroll
            for (int i = 0; i < 4; ++i)
#pragma unroll
                for (int j = 0; j < 2; ++j)
                    acc[i][j] = __builtin_amdgcn_mfma_f32_16x16x32_bf16(af[i], bf[j],
                                                                        acc[i][j], 0, 0, 0);
        }
        __syncthreads();
    }

    int outf32 = *flag;
#pragma unroll
    for (int j = 0; j < 2; ++j) {
        int n = n0 + wave * 32 + j * 16 + l16;
        float bv = bias[n];
#pragma unroll
        for (int i = 0; i < 4; ++i)
#pragma unroll
            for (int r = 0; r < 4; ++r) {
                int m = m0 + i * 16 + quad * 4 + r;
                float v = acc[i][j][r] + bv;
                if (outf32) ((float*)out)[(size_t)m * D_DIM + n] = v;
                else        ((ushort*)out)[(size_t)m * D_DIM + n] = f2bf(v);
            }
    }
}

// ---------------------------------------------------------------------------
// Causal attention v8: v7 + UNIFORM PAIRED JOBS.
// v7 analysis: 2048 one-wave jobs vs ~2048-wave capacity -> ALL jobs resident
// at launch, NO backfill. Static assignment gives SIMD-level imbalance up to
// 2:1 (a SIMD holding qt={15,7} runs 48 tiles while qt={1,9} runs 24 then
// idles) -> tail set by unluckiest SIMD. Fix: pair complementary jobs.
// thw(qt,w) = 2qt+(w>>1)+1; pair (qt,w) with (15-qt,3-w): sum = 33 ALWAYS.
// Each wave runs sub-job A (qt>=8) then sub-job B sequentially -- same regs,
// own rsum/epilogue per sub, zero sync, verified v7 tile body unchanged.
// 1024 blocks = 4/CU = 1 wave/SIMD, perfectly uniform; XCD pin retained.
// ---------------------------------------------------------------------------
#define LOADK(DST, T) { size_t _b = Kbase + (size_t)(T) * 4096 + lane8;           \
    _Pragma("unroll") for (int _i = 0; _i < 8; ++_i)                              \
        DST[_i] = *(const bf16x8*)&Kp[_b + (size_t)((_i >> 2) * 2048 + (_i & 3) * 512)]; }

#define LOADV(DST, T) { size_t _b = Vbase + (size_t)(T) * 4096 + lane8;           \
    _Pragma("unroll") for (int _i = 0; _i < 8; ++_i)                              \
        DST[_i] = *(const bf16x8*)&Vp[_b + (size_t)((_i >> 1) * 1024 + (_i & 1) * 512)]; }

#define SOFT(SC, P0, P1) { unsigned int W[8];                                     \
    _Pragma("unroll") for (int _g = 0; _g < 4; ++_g) {                            \
        float _e0 = __builtin_amdgcn_exp2f(SC[4 * _g + 0]);                       \
        float _e1 = __builtin_amdgcn_exp2f(SC[4 * _g + 1]);                       \
        float _e2 = __builtin_amdgcn_exp2f(SC[4 * _g + 2]);                       \
        float _e3 = __builtin_amdgcn_exp2f(SC[4 * _g + 3]);                       \
        rsum += (_e0 + _e1) + (_e2 + _e3);                                        \
        W[2 * _g]     = cvt_pk_bf16(_e0, _e1);                                    \
        W[2 * _g + 1] = cvt_pk_bf16(_e2, _e3); }                                  \
    pl32swap(W[0], W[2]); pl32swap(W[1], W[3]);                                   \
    pl32swap(W[4], W[6]); pl32swap(W[5], W[7]);                                   \
    { union { unsigned int u[4]; bf16x8 v; } _c0, _c1;                            \
      _c0.u[0] = W[0]; _c0.u[1] = W[1]; _c0.u[2] = W[2]; _c0.u[3] = W[3];         \
      _c1.u[0] = W[4]; _c1.u[1] = W[5]; _c1.u[2] = W[6]; _c1.u[3] = W[7];         \
      P0 = _c0.v; P1 = _c1.v; } }

#define ROUND(KC, VC, KN, VN, T, PRE) {                                           \
    if (PRE) { LOADK(KN, (T) + 1); LOADV(VN, (T) + 1); }                          \
    int k0 = (T) * 64;                                                            \
    f32x16 sc0, sc1;                                                              \
    _Pragma("unroll") for (int _r = 0; _r < 16; ++_r) { sc0[_r] = 0.f; sc1[_r] = 0.f; } \
    __builtin_amdgcn_s_setprio(1);                                                \
    _Pragma("unroll") for (int _j = 0; _j < 4; ++_j) {                            \
        sc0 = __builtin_amdgcn_mfma_f32_32x32x16_bf16(KC[_j],     qf[_j], sc0, 0, 0, 0); \
        sc1 = __builtin_amdgcn_mfma_f32_32x32x16_bf16(KC[4 + _j], qf[_j], sc1, 0, 0, 0); } \
    __builtin_amdgcn_s_setprio(0);                                                \
    if (k0 + 63 > qmin) {                                                         \
        int qglob = qmin + l31;                                                   \
        _Pragma("unroll") for (int _r = 0; _r < 16; ++_r) {                       \
            int krow = k0 + (_r & 3) + 8 * (_r >> 2) + 4 * hi;                    \
            if (krow > qglob)      sc0[_r] = -1e30f;                              \
            if (krow + 32 > qglob) sc1[_r] = -1e30f; } }                          \
    bf16x8 pf[4];                                                                 \
    SOFT(sc0, pf[0], pf[1]);                                                      \
    SOFT(sc1, pf[2], pf[3]);                                                      \
    __builtin_amdgcn_s_setprio(1);                                                \
    _Pragma("unroll") for (int _j = 0; _j < 4; ++_j) {                            \
        oo0 = __builtin_amdgcn_mfma_f32_32x32x16_bf16(pf[_j], VC[2 * _j],     oo0, 0, 0, 0); \
        oo1 = __builtin_amdgcn_mfma_f32_32x32x16_bf16(pf[_j], VC[2 * _j + 1], oo1, 0, 0, 0); } \
    __builtin_amdgcn_s_setprio(0); }

__global__ __launch_bounds__(64, 1) void attn_kernel(const ushort* __restrict__ Qg,
                                                     const ushort* __restrict__ Kp,
                                                     const ushort* __restrict__ Vp,
                                                     ushort* __restrict__ attn_out) {
    int lane = threadIdx.x;
    int l31  = lane & 31;
    int hi   = lane >> 5;
    // XCD-locality decode: bid = xcd + 8*rank; rank = bh-group | pair-index.
    int bid  = blockIdx.x;              // 0..1023
    int xcd  = bid & 7;                 // presumed XCD (round-robin bid%8)
    int rank = bid >> 3;                // 0..127 within XCD
    int bh   = xcd + 8 * (rank & 3);    // bh & 7 == xcd  (4 bh per XCD)
    int pp   = rank >> 2;               // 0..31 pair index

    size_t lane8 = (size_t)lane * 8;
    size_t Kbase = (size_t)bh * 131072;
    size_t Vbase = (size_t)bh * 131072;
    const ushort* Qb = Qg + (size_t)bh * S_DIM * HD_DIM;
    int b = bh >> 4, h = bh & 15;

    // sub 0: (qt,w) with qt in 8..15; sub 1: complement (15-qt, 3-w).
    // thw sums to exactly 33 tiles per wave -- uniform across all 1024 waves.
    for (int sub = 0; sub < 2; ++sub) {
        int qt   = sub ? (7 - (pp >> 2)) : (8 + (pp >> 2));
        int w    = sub ? (3 - (pp & 3))  : (pp & 3);
        int qmin = qt * 128 + w * 32;
        int thw  = ((qmin + 31) >> 6) + 1;   // tiles 0..thw-1

        // Q fragments (B-operand: n=query=l31, k=hd = kk*16 + hi*8 + e)
        bf16x8 qf[4];
#pragma unroll
        for (int kk = 0; kk < 4; ++kk)
            qf[kk] = *(const bf16x8*)&Qb[(size_t)(qmin + l31) * HD_DIM +
                                         kk * 16 + hi * 8];

        f32x16 oo0, oo1;
#pragma unroll
        for (int r = 0; r < 16; ++r) { oo0[r] = 0.f; oo1[r] = 0.f; }
        float rsum = 0.f;

        bf16x8 kA[8], kB[8], vA[8], vB[8];
        int t = 0;
        LOADK(kA, 0); LOADV(vA, 0);
        for (; t + 2 <= thw; t += 2) {
            ROUND(kA, vA, kB, vB, t, true);
            ROUND(kB, vB, kA, vA, t + 1, (t + 2 < thw));
        }
        if (t < thw) ROUND(kA, vA, kB, vB, t, false);

        // row sum across the two key-halves held by lanes l and l+32
        rsum += __shfl_xor(rsum, 32, 64);
        float inv = 1.f / rsum;         // lane q holds inv for query qmin+q (q<32)

        // epilogue: normalized bf16 write, C-frag row = (r&3)+8*(r>>2)+4*hi
#pragma unroll
        for (int r = 0; r < 16; ++r) {
            int qrow = (r & 3) + 8 * (r >> 2) + 4 * hi;
            float iv = __shfl(inv, qrow, 64);
            int q = qmin + qrow;
            size_t base = (size_t)(b * S_DIM + q) * D_DIM + h * HD_DIM;
            attn_out[base + l31]      = f2bf(oo0[r] * iv);
            attn_out[base + 32 + l31] = f2bf(oo1[r] * iv);
        }
    }
}

// ---------------------------------------------------------------------------
extern "C" void kernel_launch(void* const* d_in, const int* in_sizes, int n_in,
                              void* d_out, int out_size, void* d_ws, size_t ws_size,
                              hipStream_t stream) {
    const void* x  = d_in[0];
    const void* Wq = d_in[1];
    const void* bq = d_in[2];
    const void* Wk = d_in[3];
    const void* bk = d_in[4];
    const void* Wv = d_in[5];
    const void* bv = d_in[6];
    const void* Wo = d_in[7];
    const void* bo = d_in[8];
    // d_in[9] = mask: exactly causal tril, handled analytically.

    char* ws = (char*)d_ws;
    const size_t MB = 1024 * 1024;
    const size_t base = 64 * 1024;
    int*    flag   = (int*)ws;
    float*  biasf  = (float*)(ws + 4096);
    ushort* xc     = (ushort*)(ws + base);                  // 8 MiB; reused as attn later
    ushort* Wqkvt  = (ushort*)(ws + base + 8  * MB);        // 6 MiB (3072x1024)
    ushort* Wot    = (ushort*)(ws + base + 14 * MB);        // 2 MiB
    ushort* Qc     = (ushort*)(ws + base + 16 * MB);        // 8 MiB Q (BH,S,64)
    ushort* Kpf    = (ushort*)(ws + base + 24 * MB);        // 8 MiB K fragment-packed
    ushort* Vpf    = (ushort*)(ws + base + 40 * MB);        // 8 MiB V fragment-packed
    ushort* attn   = xc;                                    // xc dead before attn writes

    dim3 tb(256);

    detect_kernel<<<1, tb, 0, stream>>>((const ushort*)x, flag);

    dim3 pg(16, 16, 6);
    prep_kernel<<<pg, tb, 0, stream>>>(x, Wq, Wk, Wv, Wo, bq, bk, bv, bo,
                                       xc, Wqkvt, Wot, biasf, flag);

    // Fused QKV projection: (4096x1024) x (3072x1024)^T
    dim3 gq(3 * D_DIM / 128, (B_DIM * S_DIM) / 128);   // (24, 32)
    gemm128_kernel<<<gq, tb, 0, stream>>>(x, xc, Wqkvt, biasf, Qc, Kpf, Vpf, flag);

    attn_kernel<<<1024, dim3(64), 0, stream>>>(Qc, Kpf, Vpf, attn);

    dim3 go(D_DIM / 128, (B_DIM * S_DIM) / 64);        // (8, 64) = 512 blocks
    gemm64_kernel<<<go, tb, 0, stream>>>(attn, Wot, biasf + 3072, d_out, flag);
}